// Round 6
// baseline (3277.271 us; speedup 1.0000x reference)
//
#include <hip/hip_runtime.h>
#include <math.h>

#define NB_B 16
#define NB_S 4096
#define NB_D 64
#define NB_H 8

// LDS strides (in halfs) chosen so rows are 16B-aligned: 72*2=144=16*9,
// 136*2=272=16*17 -> every MFMA fragment is a single ds_read_b128.
#define KSTR 72
#define PSTR 136
#define VSTR 72

typedef _Float16 half_t;
typedef __attribute__((ext_vector_type(2))) _Float16 half2t;
typedef __attribute__((ext_vector_type(4))) _Float16 half4;
typedef __attribute__((ext_vector_type(8))) _Float16 half8;
typedef __attribute__((ext_vector_type(4))) float floatx4;

// ---------------- Kernel 0: precompute fp16 k-hat, v, f32 norm ----------------
// grid: B*S*16/256 blocks; 16 lanes per row. q = norm * khat (Q never stored).
__global__ __launch_bounds__(256) void prep_kernel(const float* __restrict__ qk,
                                                   const float* __restrict__ v,
                                                   half_t* __restrict__ khat,
                                                   half_t* __restrict__ vh,
                                                   float* __restrict__ norm) {
  int g = blockIdx.x * 256 + threadIdx.x;  // over B*S*16
  float4 qv = ((const float4*)qk)[g];
  float4 vv = ((const float4*)v)[g];
  float ss = qv.x * qv.x + qv.y * qv.y + qv.z * qv.z + qv.w * qv.w;
  for (int off = 1; off < 16; off <<= 1) ss += __shfl_xor(ss, off);
  float nr = fmaxf(sqrtf(ss), 1e-12f);
  float sc = 1.0f / nr;
  half4 hk = {(half_t)(qv.x * sc), (half_t)(qv.y * sc), (half_t)(qv.z * sc),
              (half_t)(qv.w * sc)};
  half4 hv = {(half_t)vv.x, (half_t)vv.y, (half_t)vv.z, (half_t)vv.w};
  ((half4*)khat)[g] = hk;
  ((half4*)vh)[g] = hv;
  if ((threadIdx.x & 15) == 0) norm[g >> 4] = nr;
}

// ---------------- Kernel 1: LSH hashing (buckets) ----------------
// Fast FMA path for all tokens; strict bit-faithful np.einsum-f32 mimic
// (sequential f, round(mul)+round(add)) only when top-2 gap < 1e-3
// (FMA-vs-strict deviation bound ~1e-4, so argmax is provably identical
// for all other tokens). One thread per token.
__global__ __launch_bounds__(256) void hash_kernel(const float* __restrict__ qk,
                                                   const float* __restrict__ rot,
                                                   int* __restrict__ bkt) {
  __shared__ float rotS[64 * 32];  // [f][i]
  int tid = threadIdx.x;
  int blk = blockIdx.x;
  int tile = blk & 15, bh = blk >> 4;
  int h = bh & 7, b = bh >> 3;
  int t = (tile << 8) + tid;

  for (int i = tid; i < 2048; i += 256) {
    int f = i >> 5, ii = i & 31;
    rotS[i] = rot[(((size_t)b * 64 + f) * 8 + h) * 32 + ii];
  }
  __syncthreads();

  const float4* qrow = (const float4*)(qk + (((size_t)b << 12) + t) * 64);
  float qreg[64];
#pragma unroll
  for (int j = 0; j < 16; j++) *(float4*)(qreg + 4 * j) = qrow[j];

  float acc[32];
#pragma unroll
  for (int i = 0; i < 32; i++) acc[i] = 0.f;

  // fast path: FMA accumulate
#pragma unroll
  for (int f = 0; f < 64; f++) {
    float qf = qreg[f];
#pragma unroll
    for (int i4 = 0; i4 < 8; i4++) {
      float4 w = *(const float4*)(rotS + f * 32 + i4 * 4);
      acc[i4 * 4 + 0] = fmaf(qf, w.x, acc[i4 * 4 + 0]);
      acc[i4 * 4 + 1] = fmaf(qf, w.y, acc[i4 * 4 + 1]);
      acc[i4 * 4 + 2] = fmaf(qf, w.z, acc[i4 * 4 + 2]);
      acc[i4 * 4 + 3] = fmaf(qf, w.w, acc[i4 * 4 + 3]);
    }
  }

  // top-2 over concat([acc, -acc]); strict > keeps first occurrence
  float b1 = acc[0];
  int i1 = 0;
  float b2 = -3.4e38f;
#pragma unroll
  for (int i = 1; i < 32; i++) {
    float x = acc[i];
    if (x > b1) { b2 = b1; b1 = x; i1 = i; }
    else if (x > b2) b2 = x;
  }
#pragma unroll
  for (int i = 0; i < 32; i++) {
    float x = -acc[i];
    if (x > b1) { b2 = b1; b1 = x; i1 = 32 + i; }
    else if (x > b2) b2 = x;
  }

  if (b1 - b2 < 1e-3f) {
    // strict recompute, bit-identical to np.einsum f32 accumulation order
#pragma unroll 4
    for (int i = 0; i < 32; i++) {
      float s = 0.f;
      for (int f = 0; f < 64; f++)
        s = __fadd_rn(s, __fmul_rn(qreg[f], rotS[f * 32 + i]));
      acc[i] = s;
    }
    b1 = acc[0];
    i1 = 0;
#pragma unroll
    for (int i = 1; i < 32; i++)
      if (acc[i] > b1) { b1 = acc[i]; i1 = i; }
#pragma unroll
    for (int i = 0; i < 32; i++) {
      float x = -acc[i];
      if (x > b1) { b1 = x; i1 = 32 + i; }
    }
  }
  bkt[(((size_t)(b * 8 + h)) << 12) + t] = i1;
}

// ---------------- Kernel 2: stable counting sort per (b,h) ----------------
__global__ __launch_bounds__(256) void sort_kernel(const int* __restrict__ bkt,
                                                   int* __restrict__ st) {
  __shared__ int lb[4096];
  __shared__ int hist[4096];  // [chunk(64)][bucket(64)]
  __shared__ int cumoff[64];
  int tid = threadIdx.x;
  int b = blockIdx.x >> 3, h = blockIdx.x & 7;
  const int* gb = bkt + (((size_t)(b * 8 + h)) << 12);
  for (int t = tid; t < 4096; t += 256) lb[t] = gb[t];
  for (int i = tid; i < 4096; i += 256) hist[i] = 0;
  __syncthreads();
  for (int t = tid; t < 4096; t += 256) atomicAdd(&hist[((t >> 6) << 6) | lb[t]], 1);
  __syncthreads();
  if (tid < 64) {
    int run = 0;
    for (int cc = 0; cc < 64; cc++) {
      int x = hist[(cc << 6) | tid];
      hist[(cc << 6) | tid] = run;
      run += x;
    }
    // exclusive prefix over buckets via wave-0 shfl scan
    int s = run;
    for (int off = 1; off < 64; off <<= 1) {
      int u = __shfl_up(s, off);
      if (tid >= off) s += u;
    }
    cumoff[tid] = s - run;
  }
  __syncthreads();
  int lane = tid & 63;
  for (int p = 0; p < 16; p++) {
    int t = (p << 8) + tid;  // each wave covers one aligned 64-token chunk
    int vb = lb[t];
    unsigned long long m = 0xFFFFFFFFFFFFFFFFull;
#pragma unroll
    for (int bit = 0; bit < 6; bit++) {
      unsigned long long bl = __ballot((vb >> bit) & 1);
      m &= ((vb >> bit) & 1) ? bl : ~bl;
    }
    int rank = __popcll(m & ((1ull << lane) - 1ull));
    int cpos = cumoff[vb] + hist[((t >> 6) << 6) | vb] + rank;
    st[(((size_t)(b * 8 + h)) << 12) + cpos] = t;
  }
}

// ---------------- Kernel 3: fused chunk kernel ----------------
// Per (b, round, chunk): QK^T (MFMA) -> per-round softmax -> P.V (MFMA),
// write normalized per-round output o_r (fp16) + lse_r. No atomics.
// grid: B*512 blocks, 256 threads = 4 waves.
__global__ __launch_bounds__(256) void chunk_kernel(const half_t* __restrict__ khat,
                                                    const half_t* __restrict__ vh,
                                                    const float* __restrict__ norm,
                                                    const int* __restrict__ st,
                                                    half_t* __restrict__ oh,
                                                    float* __restrict__ lse) {
  __shared__ __align__(16) half_t Ks[128 * KSTR];  // K; later P (64 rows, PSTR)
  __shared__ __align__(16) half_t Vt[64 * VSTR];   // V^T half: [dim][key]; later O
  __shared__ int tk[128];
  __shared__ float normS[64];
  int tid = threadIdx.x;
  int g = blockIdx.x & 511;
  int b = blockIdx.x >> 9;
  int h = g >> 6, c = g & 63;
  int gp = (g + 511) & 511;
  int hp = gp >> 6, cp = gp & 63;
  if (tid < 64) {
    tk[tid] = st[(((size_t)(b * 8 + h)) << 12) + (c << 6) + tid];
  } else if (tid < 128) {
    tk[tid] = st[(((size_t)(b * 8 + hp)) << 12) + (cp << 6) + (tid - 64)];
  }
  __syncthreads();
  if (tid < 64) normS[tid] = norm[(b << 12) + tk[tid]];
  // stage K (128 rows): single b128 load -> single b128 LDS store
  for (int idx = tid; idx < 1024; idx += 256) {
    int row = idx >> 3, fo = idx & 7;
    half8 val = *(const half8*)(khat + (((size_t)(b << 12) + tk[row]) << 6) + fo * 8);
    *(half8*)(Ks + row * KSTR + fo * 8) = val;
  }
  // stage V half 0 (keys 0..63) transposed
  {
    int kp = tid & 31, ch = tid >> 5;  // ch in 0..7
    half8 r0 = *(const half8*)(vh + (((size_t)(b << 12) + tk[2 * kp]) << 6) + ch * 8);
    half8 r1 = *(const half8*)(vh + (((size_t)(b << 12) + tk[2 * kp + 1]) << 6) + ch * 8);
#pragma unroll
    for (int j = 0; j < 8; j++) {
      half2t pr = {r0[j], r1[j]};
      *(half2t*)(Vt + (ch * 8 + j) * VSTR + 2 * kp) = pr;
    }
  }
  __syncthreads();

  int lane = tid & 63, w = tid >> 6;
  int m = lane & 15, quad = lane >> 4;
  half8 afr[2];
#pragma unroll
  for (int ki = 0; ki < 2; ki++)
    afr[ki] = *(const half8*)(Ks + (w * 16 + m) * KSTR + ki * 32 + quad * 8);
  int ti[4];
  float scr[4];
#pragma unroll
  for (int r = 0; r < 4; r++) {
    int rr = w * 16 + quad * 4 + r;
    ti[r] = tk[rr];
    scr[r] = 0.125f * normS[rr];
  }

  // QK^T dots, masked + scaled
  float d[8][4];
#pragma unroll
  for (int nt = 0; nt < 8; nt++) {
    floatx4 acc = {0.f, 0.f, 0.f, 0.f};
#pragma unroll
    for (int ki = 0; ki < 2; ki++) {
      half8 bfr = *(const half8*)(Ks + (nt * 16 + m) * KSTR + ki * 32 + quad * 8);
      acc = __builtin_amdgcn_mfma_f32_16x16x32_f16(afr[ki], bfr, acc, 0, 0, 0);
    }
    int tj = tk[nt * 16 + m];
#pragma unroll
    for (int r = 0; r < 4; r++)
      d[nt][r] = (ti[r] == tj) ? -50000.0f : acc[r] * scr[r];
  }

  // per-round row softmax stats (over the 128 keys)
  float mr[4], lr[4];
#pragma unroll
  for (int r = 0; r < 4; r++) {
    float mm = d[0][r];
#pragma unroll
    for (int nt = 1; nt < 8; nt++) mm = fmaxf(mm, d[nt][r]);
    for (int off = 1; off < 16; off <<= 1) mm = fmaxf(mm, __shfl_xor(mm, off));
    float ll = 0.f;
#pragma unroll
    for (int nt = 0; nt < 8; nt++) ll += __expf(d[nt][r] - mm);
    for (int off = 1; off < 16; off <<= 1) ll += __shfl_xor(ll, off);
    mr[r] = mm;
    lr[r] = ll;
    if (m == 0) lse[(((size_t)(b * 8 + h)) << 12) + ti[r]] = mm + __logf(ll);
  }
  __syncthreads();  // all waves done reading Ks as K

  // P' = exp(d - m_r) fp16 into Ks region (stride PSTR)
  half_t* Ps = Ks;
#pragma unroll
  for (int nt = 0; nt < 8; nt++) {
#pragma unroll
    for (int r = 0; r < 4; r++) {
      Ps[(w * 16 + quad * 4 + r) * PSTR + nt * 16 + m] = (half_t)__expf(d[nt][r] - mr[r]);
    }
  }
  __syncthreads();

  half8 pfr[4];
#pragma unroll
  for (int kk = 0; kk < 4; kk++)
    pfr[kk] = *(const half8*)(Ps + (w * 16 + m) * PSTR + kk * 32 + quad * 8);

  floatx4 accO[4];
#pragma unroll
  for (int dt = 0; dt < 4; dt++) accO[dt] = (floatx4){0.f, 0.f, 0.f, 0.f};

  // PV with V half 0 (keys 0..63 -> pfr 0,1)
#pragma unroll
  for (int dt = 0; dt < 4; dt++) {
#pragma unroll
    for (int kk = 0; kk < 2; kk++) {
      half8 bfr = *(const half8*)(Vt + (dt * 16 + m) * VSTR + kk * 32 + quad * 8);
      accO[dt] = __builtin_amdgcn_mfma_f32_16x16x32_f16(pfr[kk], bfr, accO[dt], 0, 0, 0);
    }
  }
  __syncthreads();  // V half 0 reads done

  // stage V half 1 (keys 64..127)
  {
    int kp = tid & 31, ch = tid >> 5;
    half8 r0 = *(const half8*)(vh + (((size_t)(b << 12) + tk[64 + 2 * kp]) << 6) + ch * 8);
    half8 r1 = *(const half8*)(vh + (((size_t)(b << 12) + tk[65 + 2 * kp]) << 6) + ch * 8);
#pragma unroll
    for (int j = 0; j < 8; j++) {
      half2t pr = {r0[j], r1[j]};
      *(half2t*)(Vt + (ch * 8 + j) * VSTR + 2 * kp) = pr;
    }
  }
  __syncthreads();

  // PV with V half 1 (keys 64..127 -> pfr 2,3)
#pragma unroll
  for (int dt = 0; dt < 4; dt++) {
#pragma unroll
    for (int kk = 2; kk < 4; kk++) {
      half8 bfr = *(const half8*)(Vt + (dt * 16 + m) * VSTR + (kk - 2) * 32 + quad * 8);
      accO[dt] = __builtin_amdgcn_mfma_f32_16x16x32_f16(pfr[kk], bfr, accO[dt], 0, 0, 0);
    }
  }
  __syncthreads();  // PV half 1 reads of Vt done; reuse Vt for O

  // normalized O (fp16) -> LDS, then coalesced 16B row stores
  half_t* Ot = Vt;
#pragma unroll
  for (int r = 0; r < 4; r++) {
    float inv = 1.0f / lr[r];
#pragma unroll
    for (int dt = 0; dt < 4; dt++) {
      Ot[(w * 16 + quad * 4 + r) * VSTR + dt * 16 + m] = (half_t)(accO[dt][r] * inv);
    }
  }
  __syncthreads();
  for (int idx = tid; idx < 512; idx += 256) {
    int row = idx >> 3, fo = idx & 7;
    half8 val = *(const half8*)(Ot + row * VSTR + fo * 8);
    *(half8*)(oh + ((((size_t)(b * 8 + h)) << 12) + tk[row]) * 64 + fo * 8) = val;
  }
}

// ---------------- Kernel 4: combine rounds ----------------
// out[b,t,:] = sum_r exp(lse_r - lse_tot) * o_r[b,t,:]
// grid: B*S*8/256 blocks; thread = (token, 8-dim group)
__global__ __launch_bounds__(256) void combine_kernel(const half_t* __restrict__ oh,
                                                      const float* __restrict__ lse,
                                                      float* __restrict__ out) {
  int idx = blockIdx.x * 256 + threadIdx.x;  // over B*S*8
  int do8 = idx & 7;
  int ts = idx >> 3;  // b*4096 + t
  int b = ts >> 12, t = ts & 4095;
  size_t base = ((size_t)b << 15) + t;  // (b*8)<<12 + t
  float L[8];
  float m = -3.4e38f;
#pragma unroll
  for (int h = 0; h < 8; h++) {
    L[h] = lse[base + ((size_t)h << 12)];
    m = fmaxf(m, L[h]);
  }
  float s = 0.f;
#pragma unroll
  for (int h = 0; h < 8; h++) s += __expf(L[h] - m);
  float lt = m + __logf(s);
  float acc[8];
#pragma unroll
  for (int j = 0; j < 8; j++) acc[j] = 0.f;
#pragma unroll
  for (int h = 0; h < 8; h++) {
    float wgt = __expf(L[h] - lt);
    half8 o = *(const half8*)(oh + ((base + ((size_t)h << 12)) << 6) + do8 * 8);
#pragma unroll
    for (int j = 0; j < 8; j++) acc[j] += wgt * (float)o[j];
  }
  float* dst = out + ((((size_t)b << 12) + t) << 6) + do8 * 8;
  *(float4*)dst = (float4){acc[0], acc[1], acc[2], acc[3]};
  *(float4*)(dst + 4) = (float4){acc[4], acc[5], acc[6], acc[7]};
}

extern "C" void kernel_launch(void* const* d_in, const int* in_sizes, int n_in,
                              void* d_out, int out_size, void* d_ws, size_t ws_size,
                              hipStream_t stream) {
  const float* qk = (const float*)d_in[0];
  const float* v = (const float*)d_in[1];
  const float* rot = (const float*)d_in[2];
  float* out = (float*)d_out;

  int* bkt = (int*)d_ws;                            // 2MB
  int* stp = bkt + NB_B * NB_H * NB_S;              // 2MB
  float* lse = (float*)(stp + NB_B * NB_H * NB_S);  // 2MB
  float* norm = lse + NB_B * NB_H * NB_S;           // 256KB
  half_t* khat = (half_t*)(norm + NB_B * NB_S);     // 8MB
  half_t* vh = khat + (size_t)NB_B * NB_S * NB_D;   // 8MB
  half_t* oh = vh + (size_t)NB_B * NB_S * NB_D;     // B*H*S*D fp16 = 67MB

  prep_kernel<<<NB_B * NB_S * 16 / 256, 256, 0, stream>>>(qk, v, khat, vh, norm);
  hash_kernel<<<NB_B * NB_H * 16, 256, 0, stream>>>(qk, rot, bkt);
  sort_kernel<<<NB_B * NB_H, 256, 0, stream>>>(bkt, stp);
  chunk_kernel<<<NB_B * 512, 256, 0, stream>>>(khat, vh, norm, stp, oh, lse);
  combine_kernel<<<NB_B * NB_S * 8 / 256, 256, 0, stream>>>(oh, lse, out);
}

// Round 7
// 214.112 us; speedup vs baseline: 15.3064x; 15.3064x over previous
//
#include <hip/hip_runtime.h>
#include <math.h>

#define NB_B 16
#define NB_S 4096
#define NB_D 64
#define NB_H 8

// LDS strides (in halfs) chosen so rows are 16B-aligned: 72*2=144=16*9,
// 136*2=272=16*17 -> every MFMA fragment is a single ds_read_b128.
#define KSTR 72
#define PSTR 136
#define VSTR 72

typedef _Float16 half_t;
typedef __attribute__((ext_vector_type(2))) _Float16 half2t;
typedef __attribute__((ext_vector_type(4))) _Float16 half4;
typedef __attribute__((ext_vector_type(8))) _Float16 half8;
typedef __attribute__((ext_vector_type(4))) float floatx4;

// ---------------- Kernel 0: precompute fp16 k-hat, v, f32 norm ----------------
// grid: B*S*16/256 blocks; 16 lanes per row. q = norm * khat (Q never stored).
__global__ __launch_bounds__(256) void prep_kernel(const float* __restrict__ qk,
                                                   const float* __restrict__ v,
                                                   half_t* __restrict__ khat,
                                                   half_t* __restrict__ vh,
                                                   float* __restrict__ norm) {
  int g = blockIdx.x * 256 + threadIdx.x;  // over B*S*16
  float4 qv = ((const float4*)qk)[g];
  float4 vv = ((const float4*)v)[g];
  float ss = qv.x * qv.x + qv.y * qv.y + qv.z * qv.z + qv.w * qv.w;
  for (int off = 1; off < 16; off <<= 1) ss += __shfl_xor(ss, off);
  float nr = fmaxf(sqrtf(ss), 1e-12f);
  float sc = 1.0f / nr;
  half4 hk = {(half_t)(qv.x * sc), (half_t)(qv.y * sc), (half_t)(qv.z * sc),
              (half_t)(qv.w * sc)};
  half4 hv = {(half_t)vv.x, (half_t)vv.y, (half_t)vv.z, (half_t)vv.w};
  ((half4*)khat)[g] = hk;
  ((half4*)vh)[g] = hv;
  if ((threadIdx.x & 15) == 0) norm[g >> 4] = nr;
}

// ---------------- Kernel 1: LSH hashing (buckets) ----------------
// Bit-faithful mimic of naive np.einsum float32 (keeps bucket decisions
// identical to the harness reference). One thread per token. SINGLE loop
// nest, no fallback branch — the R6 "fast path + strict fallback" variant
// made the compiler demote qreg/acc to scratch (VGPR=256, 6.8 GB spill
// traffic, 3.1 ms). Do not reintroduce a second path in this kernel.
__global__ __launch_bounds__(256) void hash_kernel(const float* __restrict__ qk,
                                                   const float* __restrict__ rot,
                                                   int* __restrict__ bkt) {
  __shared__ float rotS[64 * 32];  // [f][i]
  int tid = threadIdx.x;
  int blk = blockIdx.x;
  int tile = blk & 15, bh = blk >> 4;
  int h = bh & 7, b = bh >> 3;
  int t = (tile << 8) + tid;

  for (int i = tid; i < 2048; i += 256) {
    int f = i >> 5, ii = i & 31;
    rotS[i] = rot[(((size_t)b * 64 + f) * 8 + h) * 32 + ii];
  }
  __syncthreads();

  const float4* qrow = (const float4*)(qk + (((size_t)b << 12) + t) * 64);
  float qreg[64];
#pragma unroll
  for (int j = 0; j < 16; j++) *(float4*)(qreg + 4 * j) = qrow[j];

  float acc[32];
#pragma unroll
  for (int i = 0; i < 32; i++) acc[i] = 0.f;

#pragma unroll
  for (int f = 0; f < 64; f++) {
    float qf = qreg[f];
#pragma unroll
    for (int i4 = 0; i4 < 8; i4++) {
      float4 w = *(const float4*)(rotS + f * 32 + i4 * 4);
      acc[i4 * 4 + 0] = __fadd_rn(acc[i4 * 4 + 0], __fmul_rn(qf, w.x));
      acc[i4 * 4 + 1] = __fadd_rn(acc[i4 * 4 + 1], __fmul_rn(qf, w.y));
      acc[i4 * 4 + 2] = __fadd_rn(acc[i4 * 4 + 2], __fmul_rn(qf, w.z));
      acc[i4 * 4 + 3] = __fadd_rn(acc[i4 * 4 + 3], __fmul_rn(qf, w.w));
    }
  }

  float b1 = acc[0];
  int i1 = 0;
#pragma unroll
  for (int i = 1; i < 32; i++)
    if (acc[i] > b1) { b1 = acc[i]; i1 = i; }
#pragma unroll
  for (int i = 0; i < 32; i++) {
    float x = -acc[i];
    if (x > b1) { b1 = x; i1 = 32 + i; }
  }
  bkt[(((size_t)(b * 8 + h)) << 12) + t] = i1;
}

// ---------------- Kernel 2: stable counting sort per (b,h) ----------------
__global__ __launch_bounds__(256) void sort_kernel(const int* __restrict__ bkt,
                                                   int* __restrict__ st) {
  __shared__ int lb[4096];
  __shared__ int hist[4096];  // [chunk(64)][bucket(64)]
  __shared__ int cumoff[64];
  int tid = threadIdx.x;
  int b = blockIdx.x >> 3, h = blockIdx.x & 7;
  const int* gb = bkt + (((size_t)(b * 8 + h)) << 12);
  for (int t = tid; t < 4096; t += 256) lb[t] = gb[t];
  for (int i = tid; i < 4096; i += 256) hist[i] = 0;
  __syncthreads();
  for (int t = tid; t < 4096; t += 256) atomicAdd(&hist[((t >> 6) << 6) | lb[t]], 1);
  __syncthreads();
  if (tid < 64) {
    int run = 0;
    for (int cc = 0; cc < 64; cc++) {
      int x = hist[(cc << 6) | tid];
      hist[(cc << 6) | tid] = run;
      run += x;
    }
    // exclusive prefix over buckets via wave-0 shfl scan
    int s = run;
    for (int off = 1; off < 64; off <<= 1) {
      int u = __shfl_up(s, off);
      if (tid >= off) s += u;
    }
    cumoff[tid] = s - run;
  }
  __syncthreads();
  int lane = tid & 63;
  for (int p = 0; p < 16; p++) {
    int t = (p << 8) + tid;  // each wave covers one aligned 64-token chunk
    int vb = lb[t];
    unsigned long long m = 0xFFFFFFFFFFFFFFFFull;
#pragma unroll
    for (int bit = 0; bit < 6; bit++) {
      unsigned long long bl = __ballot((vb >> bit) & 1);
      m &= ((vb >> bit) & 1) ? bl : ~bl;
    }
    int rank = __popcll(m & ((1ull << lane) - 1ull));
    int cpos = cumoff[vb] + hist[((t >> 6) << 6) | vb] + rank;
    st[(((size_t)(b * 8 + h)) << 12) + cpos] = t;
  }
}

// ---------------- Kernel 3: fused chunk kernel ----------------
// Per (b, round, chunk): QK^T (MFMA) -> per-round softmax -> P.V (MFMA),
// write normalized per-round output o_r (fp16) + lse_r. No atomics.
// grid: B*512 blocks, 256 threads = 4 waves.
__global__ __launch_bounds__(256) void chunk_kernel(const half_t* __restrict__ khat,
                                                    const half_t* __restrict__ vh,
                                                    const float* __restrict__ norm,
                                                    const int* __restrict__ st,
                                                    half_t* __restrict__ oh,
                                                    float* __restrict__ lse) {
  __shared__ __align__(16) half_t Ks[128 * KSTR];  // K; later P (64 rows, PSTR)
  __shared__ __align__(16) half_t Vt[64 * VSTR];   // V^T half: [dim][key]; later O
  __shared__ int tk[128];
  __shared__ float normS[64];
  int tid = threadIdx.x;
  int g = blockIdx.x & 511;
  int b = blockIdx.x >> 9;
  int h = g >> 6, c = g & 63;
  int gp = (g + 511) & 511;
  int hp = gp >> 6, cp = gp & 63;
  if (tid < 64) {
    tk[tid] = st[(((size_t)(b * 8 + h)) << 12) + (c << 6) + tid];
  } else if (tid < 128) {
    tk[tid] = st[(((size_t)(b * 8 + hp)) << 12) + (cp << 6) + (tid - 64)];
  }
  __syncthreads();
  if (tid < 64) normS[tid] = norm[(b << 12) + tk[tid]];
  // stage K (128 rows): single b128 load -> single b128 LDS store
  for (int idx = tid; idx < 1024; idx += 256) {
    int row = idx >> 3, fo = idx & 7;
    half8 val = *(const half8*)(khat + (((size_t)(b << 12) + tk[row]) << 6) + fo * 8);
    *(half8*)(Ks + row * KSTR + fo * 8) = val;
  }
  // stage V half 0 (keys 0..63) transposed
  {
    int kp = tid & 31, ch = tid >> 5;  // ch in 0..7
    half8 r0 = *(const half8*)(vh + (((size_t)(b << 12) + tk[2 * kp]) << 6) + ch * 8);
    half8 r1 = *(const half8*)(vh + (((size_t)(b << 12) + tk[2 * kp + 1]) << 6) + ch * 8);
#pragma unroll
    for (int j = 0; j < 8; j++) {
      half2t pr = {r0[j], r1[j]};
      *(half2t*)(Vt + (ch * 8 + j) * VSTR + 2 * kp) = pr;
    }
  }
  __syncthreads();

  int lane = tid & 63, w = tid >> 6;
  int m = lane & 15, quad = lane >> 4;
  half8 afr[2];
#pragma unroll
  for (int ki = 0; ki < 2; ki++)
    afr[ki] = *(const half8*)(Ks + (w * 16 + m) * KSTR + ki * 32 + quad * 8);
  int ti[4];
  float scr[4];
#pragma unroll
  for (int r = 0; r < 4; r++) {
    int rr = w * 16 + quad * 4 + r;
    ti[r] = tk[rr];
    scr[r] = 0.125f * normS[rr];
  }

  // QK^T dots, masked + scaled
  float d[8][4];
#pragma unroll
  for (int nt = 0; nt < 8; nt++) {
    floatx4 acc = {0.f, 0.f, 0.f, 0.f};
#pragma unroll
    for (int ki = 0; ki < 2; ki++) {
      half8 bfr = *(const half8*)(Ks + (nt * 16 + m) * KSTR + ki * 32 + quad * 8);
      acc = __builtin_amdgcn_mfma_f32_16x16x32_f16(afr[ki], bfr, acc, 0, 0, 0);
    }
    int tj = tk[nt * 16 + m];
#pragma unroll
    for (int r = 0; r < 4; r++)
      d[nt][r] = (ti[r] == tj) ? -50000.0f : acc[r] * scr[r];
  }

  // per-round row softmax stats (over the 128 keys)
  float mr[4], lr[4];
#pragma unroll
  for (int r = 0; r < 4; r++) {
    float mm = d[0][r];
#pragma unroll
    for (int nt = 1; nt < 8; nt++) mm = fmaxf(mm, d[nt][r]);
    for (int off = 1; off < 16; off <<= 1) mm = fmaxf(mm, __shfl_xor(mm, off));
    float ll = 0.f;
#pragma unroll
    for (int nt = 0; nt < 8; nt++) ll += __expf(d[nt][r] - mm);
    for (int off = 1; off < 16; off <<= 1) ll += __shfl_xor(ll, off);
    mr[r] = mm;
    lr[r] = ll;
    if (m == 0) lse[(((size_t)(b * 8 + h)) << 12) + ti[r]] = mm + __logf(ll);
  }
  __syncthreads();  // all waves done reading Ks as K

  // P' = exp(d - m_r) fp16 into Ks region (stride PSTR)
  half_t* Ps = Ks;
#pragma unroll
  for (int nt = 0; nt < 8; nt++) {
#pragma unroll
    for (int r = 0; r < 4; r++) {
      Ps[(w * 16 + quad * 4 + r) * PSTR + nt * 16 + m] = (half_t)__expf(d[nt][r] - mr[r]);
    }
  }
  __syncthreads();

  half8 pfr[4];
#pragma unroll
  for (int kk = 0; kk < 4; kk++)
    pfr[kk] = *(const half8*)(Ps + (w * 16 + m) * PSTR + kk * 32 + quad * 8);

  floatx4 accO[4];
#pragma unroll
  for (int dt = 0; dt < 4; dt++) accO[dt] = (floatx4){0.f, 0.f, 0.f, 0.f};

  // PV with V half 0 (keys 0..63 -> pfr 0,1)
#pragma unroll
  for (int dt = 0; dt < 4; dt++) {
#pragma unroll
    for (int kk = 0; kk < 2; kk++) {
      half8 bfr = *(const half8*)(Vt + (dt * 16 + m) * VSTR + kk * 32 + quad * 8);
      accO[dt] = __builtin_amdgcn_mfma_f32_16x16x32_f16(pfr[kk], bfr, accO[dt], 0, 0, 0);
    }
  }
  __syncthreads();  // V half 0 reads done

  // stage V half 1 (keys 64..127)
  {
    int kp = tid & 31, ch = tid >> 5;
    half8 r0 = *(const half8*)(vh + (((size_t)(b << 12) + tk[64 + 2 * kp]) << 6) + ch * 8);
    half8 r1 = *(const half8*)(vh + (((size_t)(b << 12) + tk[65 + 2 * kp]) << 6) + ch * 8);
#pragma unroll
    for (int j = 0; j < 8; j++) {
      half2t pr = {r0[j], r1[j]};
      *(half2t*)(Vt + (ch * 8 + j) * VSTR + 2 * kp) = pr;
    }
  }
  __syncthreads();

  // PV with V half 1 (keys 64..127 -> pfr 2,3)
#pragma unroll
  for (int dt = 0; dt < 4; dt++) {
#pragma unroll
    for (int kk = 2; kk < 4; kk++) {
      half8 bfr = *(const half8*)(Vt + (dt * 16 + m) * VSTR + (kk - 2) * 32 + quad * 8);
      accO[dt] = __builtin_amdgcn_mfma_f32_16x16x32_f16(pfr[kk], bfr, accO[dt], 0, 0, 0);
    }
  }
  __syncthreads();  // PV half 1 reads of Vt done; reuse Vt for O

  // normalized O (fp16) -> LDS, then coalesced 16B row stores
  half_t* Ot = Vt;
#pragma unroll
  for (int r = 0; r < 4; r++) {
    float inv = 1.0f / lr[r];
#pragma unroll
    for (int dt = 0; dt < 4; dt++) {
      Ot[(w * 16 + quad * 4 + r) * VSTR + dt * 16 + m] = (half_t)(accO[dt][r] * inv);
    }
  }
  __syncthreads();
  for (int idx = tid; idx < 512; idx += 256) {
    int row = idx >> 3, fo = idx & 7;
    half8 val = *(const half8*)(Ot + row * VSTR + fo * 8);
    *(half8*)(oh + ((((size_t)(b * 8 + h)) << 12) + tk[row]) * 64 + fo * 8) = val;
  }
}

// ---------------- Kernel 4: combine rounds ----------------
// out[b,t,:] = sum_r exp(lse_r - lse_tot) * o_r[b,t,:]
// grid: B*S*8/256 blocks; thread = (token, 8-dim group)
__global__ __launch_bounds__(256) void combine_kernel(const half_t* __restrict__ oh,
                                                      const float* __restrict__ lse,
                                                      float* __restrict__ out) {
  int idx = blockIdx.x * 256 + threadIdx.x;  // over B*S*8
  int do8 = idx & 7;
  int ts = idx >> 3;  // b*4096 + t
  int b = ts >> 12, t = ts & 4095;
  size_t base = ((size_t)b << 15) + t;  // (b*8)<<12 + t
  float L[8];
  float m = -3.4e38f;
#pragma unroll
  for (int h = 0; h < 8; h++) {
    L[h] = lse[base + ((size_t)h << 12)];
    m = fmaxf(m, L[h]);
  }
  float s = 0.f;
#pragma unroll
  for (int h = 0; h < 8; h++) s += __expf(L[h] - m);
  float lt = m + __logf(s);
  float acc[8];
#pragma unroll
  for (int j = 0; j < 8; j++) acc[j] = 0.f;
#pragma unroll
  for (int h = 0; h < 8; h++) {
    float wgt = __expf(L[h] - lt);
    half8 o = *(const half8*)(oh + ((base + ((size_t)h << 12)) << 6) + do8 * 8);
#pragma unroll
    for (int j = 0; j < 8; j++) acc[j] += wgt * (float)o[j];
  }
  float* dst = out + ((((size_t)b << 12) + t) << 6) + do8 * 8;
  *(float4*)dst = (float4){acc[0], acc[1], acc[2], acc[3]};
  *(float4*)(dst + 4) = (float4){acc[4], acc[5], acc[6], acc[7]};
}

extern "C" void kernel_launch(void* const* d_in, const int* in_sizes, int n_in,
                              void* d_out, int out_size, void* d_ws, size_t ws_size,
                              hipStream_t stream) {
  const float* qk = (const float*)d_in[0];
  const float* v = (const float*)d_in[1];
  const float* rot = (const float*)d_in[2];
  float* out = (float*)d_out;

  int* bkt = (int*)d_ws;                            // 2MB
  int* stp = bkt + NB_B * NB_H * NB_S;              // 2MB
  float* lse = (float*)(stp + NB_B * NB_H * NB_S);  // 2MB
  float* norm = lse + NB_B * NB_H * NB_S;           // 256KB
  half_t* khat = (half_t*)(norm + NB_B * NB_S);     // 8MB
  half_t* vh = khat + (size_t)NB_B * NB_S * NB_D;   // 8MB
  half_t* oh = vh + (size_t)NB_B * NB_S * NB_D;     // B*H*S*D fp16 = 67MB

  prep_kernel<<<NB_B * NB_S * 16 / 256, 256, 0, stream>>>(qk, v, khat, vh, norm);
  hash_kernel<<<NB_B * NB_H * 16, 256, 0, stream>>>(qk, rot, bkt);
  sort_kernel<<<NB_B * NB_H, 256, 0, stream>>>(bkt, stp);
  chunk_kernel<<<NB_B * 512, 256, 0, stream>>>(khat, vh, norm, stp, oh, lse);
  combine_kernel<<<NB_B * NB_S * 8 / 256, 256, 0, stream>>>(oh, lse, out);
}